// Round 1
// baseline (733.840 us; speedup 1.0000x reference)
//
#include <hip/hip_runtime.h>
#include <math.h>

#define BB 32
#define CC 256
#define NPIX 1024     // 32*32
#define KD 16
#define NHEADS 4
#define VDIM 64
#define RR 23
#define PADR 11
#define EPSBN 1e-5f

// ---------------- K1: fused 144-channel 1x1-conv (GEMM) ----------------
// grid (32 n-tiles, B), block 256 = 32 n-lanes x 8 o-groups of 18 channels.
// rows 0..63 = Wq, 64..79 = Wk, 80..143 = Wv
__global__ __launch_bounds__(256) void k_proj(const float* __restrict__ x,
    const float* __restrict__ Wq, const float* __restrict__ Wk, const float* __restrict__ Wv,
    float* __restrict__ q_pre, float* __restrict__ k_pre, float* __restrict__ v_pre) {
  __shared__ float wlds[144 * 64];
  int b = blockIdx.y;
  int n = blockIdx.x * 32 + (threadIdx.x & 31);
  int og = threadIdx.x >> 5;   // 0..7
  float acc[18];
#pragma unroll
  for (int j = 0; j < 18; ++j) acc[j] = 0.f;
  for (int c0 = 0; c0 < CC; c0 += 64) {
    __syncthreads();
    for (int idx = threadIdx.x; idx < 144 * 64; idx += 256) {
      int row = idx >> 6, cc = idx & 63;
      const float* src = (row < 64) ? (Wq + (size_t)row * CC)
                        : (row < 80) ? (Wk + (size_t)(row - 64) * CC)
                                     : (Wv + (size_t)(row - 80) * CC);
      wlds[idx] = src[c0 + cc];
    }
    __syncthreads();
    for (int cs = 0; cs < 64; cs += 4) {
      float x0 = x[((size_t)b * CC + c0 + cs + 0) * NPIX + n];
      float x1 = x[((size_t)b * CC + c0 + cs + 1) * NPIX + n];
      float x2 = x[((size_t)b * CC + c0 + cs + 2) * NPIX + n];
      float x3 = x[((size_t)b * CC + c0 + cs + 3) * NPIX + n];
#pragma unroll
      for (int j = 0; j < 18; ++j) {
        int o = og * 18 + j;
        const float4 w = *(const float4*)&wlds[o * 64 + cs];
        acc[j] = fmaf(x0, w.x, fmaf(x1, w.y, fmaf(x2, w.z, fmaf(x3, w.w, acc[j]))));
      }
    }
  }
#pragma unroll
  for (int j = 0; j < 18; ++j) {
    int o = og * 18 + j;
    if (o < 64)      q_pre[((size_t)b * 64 + o) * NPIX + n] = acc[j];
    else if (o < 80) k_pre[((size_t)b * 16 + (o - 64)) * NPIX + n] = acc[j];
    else             v_pre[((size_t)b * 64 + (o - 80)) * NPIX + n] = acc[j];
  }
}

// ---------------- K2a: BN batch stats -> scale/shift ----------------
// stats layout: [0..63]=qscale [64..127]=qshift [128..191]=vscale [192..255]=vshift
__global__ __launch_bounds__(256) void k_bnstats(const float* __restrict__ q_pre,
    const float* __restrict__ v_pre,
    const float* __restrict__ bn_q_w, const float* __restrict__ bn_q_b,
    const float* __restrict__ bn_v_w, const float* __restrict__ bn_v_b,
    float* __restrict__ stats) {
  int ch = blockIdx.x;            // 0..127
  bool isq = ch < 64;
  int c = isq ? ch : ch - 64;
  const float* src = (isq ? q_pre : v_pre) + (size_t)c * NPIX;
  float s = 0.f, ss = 0.f;
  for (int idx = threadIdx.x; idx < BB * NPIX; idx += 256) {
    int bb = idx >> 10, nn = idx & 1023;
    float v = src[(size_t)bb * 64 * NPIX + nn];
    s += v; ss = fmaf(v, v, ss);
  }
#pragma unroll
  for (int off = 32; off > 0; off >>= 1) {
    s += __shfl_down(s, off);
    ss += __shfl_down(ss, off);
  }
  __shared__ float sh[8];
  if ((threadIdx.x & 63) == 0) {
    sh[(threadIdx.x >> 6) * 2] = s;
    sh[(threadIdx.x >> 6) * 2 + 1] = ss;
  }
  __syncthreads();
  if (threadIdx.x == 0) {
    s = sh[0] + sh[2] + sh[4] + sh[6];
    ss = sh[1] + sh[3] + sh[5] + sh[7];
    const float inv = 1.0f / (float)(BB * NPIX);
    float mean = s * inv;
    float var = ss * inv - mean * mean;   // biased, matches jnp.var
    float rstd = rsqrtf(var + EPSBN);
    float w = isq ? bn_q_w[c] : bn_v_w[c];
    float bi = isq ? bn_q_b[c] : bn_v_b[c];
    float scale = rstd * w;
    float shift = bi - mean * scale;
    if (isq) { stats[c] = scale; stats[64 + c] = shift; }
    else     { stats[128 + c] = scale; stats[192 + c] = shift; }
  }
}

// ---------------- K2b: normalize q + transpose to [b][n][64] ----------------
__global__ __launch_bounds__(256) void k_norm_q(const float* __restrict__ q_pre,
    const float* __restrict__ stats, float* __restrict__ qT) {
  __shared__ float lds[64 * 65];
  int b = blockIdx.y, n0 = blockIdx.x * 64;
  for (int l = threadIdx.x; l < 4096; l += 256) {
    int o = l >> 6, nn = l & 63;
    float v = q_pre[((size_t)b * 64 + o) * NPIX + n0 + nn];
    lds[o * 65 + nn] = fmaf(v, stats[o], stats[64 + o]);
  }
  __syncthreads();
  for (int l = threadIdx.x; l < 4096; l += 256) {
    int nn = l >> 6, o = l & 63;
    qT[((size_t)b * NPIX + n0 + nn) * 64 + o] = lds[o * 65 + nn];
  }
}

// ---------------- K2c: normalize v in place + transposed copy ----------------
__global__ __launch_bounds__(256) void k_norm_v(float* __restrict__ vn,
    const float* __restrict__ stats, float* __restrict__ vnT) {
  __shared__ float lds[64 * 65];
  int b = blockIdx.y, n0 = blockIdx.x * 64;
  for (int l = threadIdx.x; l < 4096; l += 256) {
    int o = l >> 6, nn = l & 63;
    size_t a = ((size_t)b * 64 + o) * NPIX + n0 + nn;
    float v = fmaf(vn[a], stats[128 + o], stats[192 + o]);
    vn[a] = v;
    lds[o * 65 + nn] = v;
  }
  __syncthreads();
  for (int l = threadIdx.x; l < 4096; l += 256) {
    int nn = l >> 6, o = l & 63;
    vnT[((size_t)b * NPIX + n0 + nn) * 64 + o] = lds[o * 65 + nn];
  }
}

// ---------------- K3: softmax over N per (b,k) ----------------
__global__ __launch_bounds__(256) void k_softmax(const float* __restrict__ k_pre,
    float* __restrict__ p) {
  int b = blockIdx.y, k = blockIdx.x, t = threadIdx.x;
  const float* src = k_pre + ((size_t)b * 16 + k) * NPIX;
  float v[4];
  float mx = -1e30f;
#pragma unroll
  for (int i = 0; i < 4; ++i) { v[i] = src[t + 256 * i]; mx = fmaxf(mx, v[i]); }
#pragma unroll
  for (int off = 32; off > 0; off >>= 1) mx = fmaxf(mx, __shfl_down(mx, off));
  __shared__ float shm[4], shs[4];
  if ((t & 63) == 0) shm[t >> 6] = mx;
  __syncthreads();
  mx = fmaxf(fmaxf(shm[0], shm[1]), fmaxf(shm[2], shm[3]));
  float s = 0.f;
#pragma unroll
  for (int i = 0; i < 4; ++i) { v[i] = __expf(v[i] - mx); s += v[i]; }
#pragma unroll
  for (int off = 32; off > 0; off >>= 1) s += __shfl_down(s, off);
  if ((t & 63) == 0) shs[t >> 6] = s;
  __syncthreads();
  float r = 1.0f / (shs[0] + shs[1] + shs[2] + shs[3]);
  float* dst = p + ((size_t)b * 16 + k) * NPIX;
#pragma unroll
  for (int i = 0; i < 4; ++i) dst[t + 256 * i] = v[i] * r;
}

// ---------------- K4: lambda_c[b][k][v] = sum_n p[b][k][n] * vn[b][v][n] ----------------
__global__ __launch_bounds__(256) void k_lambda_c(const float* __restrict__ p,
    const float* __restrict__ vnT, float* __restrict__ lc) {
  __shared__ float pl[1024];
  __shared__ float red[256];
  int b = blockIdx.y, k = blockIdx.x, t = threadIdx.x;
  const float* ps = p + ((size_t)b * 16 + k) * NPIX;
  for (int l = t; l < 1024; l += 256) pl[l] = ps[l];
  __syncthreads();
  int v = t & 63, nq = t >> 6;
  const float* vt = vnT + (size_t)b * NPIX * 64;
  float acc = 0.f;
  for (int n = nq * 256; n < nq * 256 + 256; ++n)
    acc = fmaf(pl[n], vt[(size_t)n * 64 + v], acc);
  red[t] = acc;
  __syncthreads();
  if (t < 64)
    lc[((size_t)b * 16 + k) * 64 + t] = red[t] + red[64 + t] + red[128 + t] + red[192 + t];
}

// ---------------- K5: fused conv(23x23) + k-contraction + lambda_c + gamma ----------------
// block = (v, b); 256 threads; thread owns pixels (py0+8i, px), i<4; 16 k-accumulators.
__global__ __launch_bounds__(256) void k_main(const float* __restrict__ vn,
    const float* __restrict__ qT, const float* __restrict__ lc,
    const float* __restrict__ emb, const float* __restrict__ gamma,
    float* __restrict__ out) {
  __shared__ float embl[16 * 552];   // rows padded 23 -> 24 (col 23 = 0) for aligned float4
  __shared__ float img[54 * 54 + 8]; // zero-padded 32x32 image (+ slack for tail-pad reads)
  __shared__ float lcv[16];
  int b = blockIdx.y, v = blockIdx.x, t = threadIdx.x;
  for (int l = t; l < 16 * 552; l += 256) embl[l] = 0.f;
  for (int l = t; l < 54 * 54 + 8; l += 256) img[l] = 0.f;
  __syncthreads();
  for (int l = t; l < 16 * 529; l += 256) {
    int k = l / 529, d = l - k * 529;
    int dr = d / 23, dc = d - dr * 23;
    embl[k * 552 + dr * 24 + dc] = emb[l];
  }
  const float* vsrc = vn + ((size_t)b * 64 + v) * NPIX;
  for (int l = t; l < 1024; l += 256) {
    int y = l >> 5, xx = l & 31;
    img[(y + PADR) * 54 + (xx + PADR)] = vsrc[l];
  }
  if (t < 16) lcv[t] = lc[((size_t)b * 16 + t) * 64 + v];
  __syncthreads();

  float g1 = 1.0f + gamma[0];
  int px = t & 31, py0 = t >> 5;   // py0 0..7
  float acc[4][16];
#pragma unroll
  for (int i = 0; i < 4; ++i)
#pragma unroll
    for (int k = 0; k < 16; ++k) acc[i][k] = 0.f;

  for (int dr = 0; dr < RR; ++dr) {
    int rb = (py0 + dr) * 54 + px;
    for (int dc0 = 0; dc0 < 24; dc0 += 4) {
      float val[4][4];
#pragma unroll
      for (int i = 0; i < 4; ++i) {
        int a = rb + i * (8 * 54) + dc0;
        val[i][0] = img[a]; val[i][1] = img[a + 1];
        val[i][2] = img[a + 2]; val[i][3] = img[a + 3];
      }
#pragma unroll
      for (int k = 0; k < 16; ++k) {
        const float4 e = *(const float4*)&embl[k * 552 + dr * 24 + dc0];
#pragma unroll
        for (int i = 0; i < 4; ++i)
          acc[i][k] = fmaf(val[i][0], e.x, fmaf(val[i][1], e.y,
                      fmaf(val[i][2], e.z, fmaf(val[i][3], e.w, acc[i][k]))));
      }
    }
  }

#pragma unroll
  for (int i = 0; i < 4; ++i) {
    int pix = (py0 + 8 * i) * 32 + px;
    const float* qp = qT + ((size_t)b * NPIX + pix) * 64;
#pragma unroll
    for (int h = 0; h < 4; ++h) {
      float y = 0.f;
#pragma unroll
      for (int k = 0; k < 16; ++k)
        y = fmaf(qp[h * 16 + k], acc[i][k] + lcv[k], y);
      out[((size_t)b * 256 + h * 64 + v) * NPIX + pix] = g1 * y;
    }
  }
}

extern "C" void kernel_launch(void* const* d_in, const int* in_sizes, int n_in,
                              void* d_out, int out_size, void* d_ws, size_t ws_size,
                              hipStream_t stream) {
  const float* x      = (const float*)d_in[0];
  const float* Wq     = (const float*)d_in[1];
  const float* bn_q_w = (const float*)d_in[2];
  const float* bn_q_b = (const float*)d_in[3];
  const float* Wk     = (const float*)d_in[4];
  const float* Wv     = (const float*)d_in[5];
  const float* bn_v_w = (const float*)d_in[6];
  const float* bn_v_b = (const float*)d_in[7];
  const float* emb    = (const float*)d_in[8];
  const float* gamma  = (const float*)d_in[9];
  float* out = (float*)d_out;

  float* ws    = (float*)d_ws;
  float* q_pre = ws;                                     // B*64*N
  float* k_pre = q_pre + (size_t)BB * 64 * NPIX;         // B*16*N
  float* vn    = k_pre + (size_t)BB * 16 * NPIX;         // B*64*N
  float* qT    = vn    + (size_t)BB * 64 * NPIX;         // B*N*64
  float* vnT   = qT    + (size_t)BB * NPIX * 64;         // B*N*64
  float* p     = vnT   + (size_t)BB * NPIX * 64;         // B*16*N
  float* lc    = p     + (size_t)BB * 16 * NPIX;         // B*16*64
  float* stats = lc    + (size_t)BB * 16 * 64;           // 256

  k_proj    <<<dim3(32, BB), 256, 0, stream>>>(x, Wq, Wk, Wv, q_pre, k_pre, vn);
  k_bnstats <<<dim3(128),    256, 0, stream>>>(q_pre, vn, bn_q_w, bn_q_b, bn_v_w, bn_v_b, stats);
  k_norm_q  <<<dim3(16, BB), 256, 0, stream>>>(q_pre, stats, qT);
  k_norm_v  <<<dim3(16, BB), 256, 0, stream>>>(vn, stats, vnT);
  k_softmax <<<dim3(16, BB), 256, 0, stream>>>(k_pre, p);
  k_lambda_c<<<dim3(16, BB), 256, 0, stream>>>(p, vnT, lc);
  k_main    <<<dim3(64, BB), 256, 0, stream>>>(vn, qT, lc, emb, gamma, out);
}

// Round 2
// 663.773 us; speedup vs baseline: 1.1056x; 1.1056x over previous
//
#include <hip/hip_runtime.h>
#include <math.h>

#define BB 32
#define CC 256
#define NPIX 1024     // 32*32
#define KD 16
#define NHEADS 4
#define VDIM 64
#define RR 23
#define PADR 11
#define EPSBN 1e-5f

typedef short short8v __attribute__((ext_vector_type(8)));
typedef short short4v __attribute__((ext_vector_type(4)));
typedef float floatx4 __attribute__((ext_vector_type(4)));

__device__ __forceinline__ unsigned short f2bf(float f) {
  union { float f; unsigned u; } c; c.f = f;
  unsigned u = c.u;
  return (unsigned short)((u + 0x7FFFu + ((u >> 16) & 1u)) >> 16);
}

// ---------------- K1: fused 144-channel 1x1-conv (GEMM) ----------------
__global__ __launch_bounds__(256) void k_proj(const float* __restrict__ x,
    const float* __restrict__ Wq, const float* __restrict__ Wk, const float* __restrict__ Wv,
    float* __restrict__ q_pre, float* __restrict__ k_pre, float* __restrict__ v_pre) {
  __shared__ float wlds[144 * 64];
  int b = blockIdx.y;
  int n = blockIdx.x * 32 + (threadIdx.x & 31);
  int og = threadIdx.x >> 5;   // 0..7
  float acc[18];
#pragma unroll
  for (int j = 0; j < 18; ++j) acc[j] = 0.f;
  for (int c0 = 0; c0 < CC; c0 += 64) {
    __syncthreads();
    for (int idx = threadIdx.x; idx < 144 * 64; idx += 256) {
      int row = idx >> 6, cc = idx & 63;
      const float* src = (row < 64) ? (Wq + (size_t)row * CC)
                        : (row < 80) ? (Wk + (size_t)(row - 64) * CC)
                                     : (Wv + (size_t)(row - 80) * CC);
      wlds[idx] = src[c0 + cc];
    }
    __syncthreads();
    for (int cs = 0; cs < 64; cs += 4) {
      float x0 = x[((size_t)b * CC + c0 + cs + 0) * NPIX + n];
      float x1 = x[((size_t)b * CC + c0 + cs + 1) * NPIX + n];
      float x2 = x[((size_t)b * CC + c0 + cs + 2) * NPIX + n];
      float x3 = x[((size_t)b * CC + c0 + cs + 3) * NPIX + n];
#pragma unroll
      for (int j = 0; j < 18; ++j) {
        int o = og * 18 + j;
        const float4 w = *(const float4*)&wlds[o * 64 + cs];
        acc[j] = fmaf(x0, w.x, fmaf(x1, w.y, fmaf(x2, w.z, fmaf(x3, w.w, acc[j]))));
      }
    }
  }
#pragma unroll
  for (int j = 0; j < 18; ++j) {
    int o = og * 18 + j;
    if (o < 64)      q_pre[((size_t)b * 64 + o) * NPIX + n] = acc[j];
    else if (o < 80) k_pre[((size_t)b * 16 + (o - 64)) * NPIX + n] = acc[j];
    else             v_pre[((size_t)b * 64 + (o - 80)) * NPIX + n] = acc[j];
  }
}

// ---------------- K2a: BN batch stats -> scale/shift ----------------
__global__ __launch_bounds__(256) void k_bnstats(const float* __restrict__ q_pre,
    const float* __restrict__ v_pre,
    const float* __restrict__ bn_q_w, const float* __restrict__ bn_q_b,
    const float* __restrict__ bn_v_w, const float* __restrict__ bn_v_b,
    float* __restrict__ stats) {
  int ch = blockIdx.x;            // 0..127
  bool isq = ch < 64;
  int c = isq ? ch : ch - 64;
  const float* src = (isq ? q_pre : v_pre) + (size_t)c * NPIX;
  float s = 0.f, ss = 0.f;
  for (int idx = threadIdx.x; idx < BB * NPIX; idx += 256) {
    int bb = idx >> 10, nn = idx & 1023;
    float v = src[(size_t)bb * 64 * NPIX + nn];
    s += v; ss = fmaf(v, v, ss);
  }
#pragma unroll
  for (int off = 32; off > 0; off >>= 1) {
    s += __shfl_down(s, off);
    ss += __shfl_down(ss, off);
  }
  __shared__ float sh[8];
  if ((threadIdx.x & 63) == 0) {
    sh[(threadIdx.x >> 6) * 2] = s;
    sh[(threadIdx.x >> 6) * 2 + 1] = ss;
  }
  __syncthreads();
  if (threadIdx.x == 0) {
    s = sh[0] + sh[2] + sh[4] + sh[6];
    ss = sh[1] + sh[3] + sh[5] + sh[7];
    const float inv = 1.0f / (float)(BB * NPIX);
    float mean = s * inv;
    float var = ss * inv - mean * mean;
    float rstd = rsqrtf(var + EPSBN);
    float w = isq ? bn_q_w[c] : bn_v_w[c];
    float bi = isq ? bn_q_b[c] : bn_v_b[c];
    float scale = rstd * w;
    float shift = bi - mean * scale;
    if (isq) { stats[c] = scale; stats[64 + c] = shift; }
    else     { stats[128 + c] = scale; stats[192 + c] = shift; }
  }
}

// ---------------- K2b: normalize q + transpose to [b][n][64] ----------------
__global__ __launch_bounds__(256) void k_norm_q(const float* __restrict__ q_pre,
    const float* __restrict__ stats, float* __restrict__ qT) {
  __shared__ float lds[64 * 65];
  int b = blockIdx.y, n0 = blockIdx.x * 64;
  for (int l = threadIdx.x; l < 4096; l += 256) {
    int o = l >> 6, nn = l & 63;
    float v = q_pre[((size_t)b * 64 + o) * NPIX + n0 + nn];
    lds[o * 65 + nn] = fmaf(v, stats[o], stats[64 + o]);
  }
  __syncthreads();
  for (int l = threadIdx.x; l < 4096; l += 256) {
    int nn = l >> 6, o = l & 63;
    qT[((size_t)b * NPIX + n0 + nn) * 64 + o] = lds[o * 65 + nn];
  }
}

// ---------------- K2c: normalize v in place + transposed copy ----------------
__global__ __launch_bounds__(256) void k_norm_v(float* __restrict__ vn,
    const float* __restrict__ stats, float* __restrict__ vnT) {
  __shared__ float lds[64 * 65];
  int b = blockIdx.y, n0 = blockIdx.x * 64;
  for (int l = threadIdx.x; l < 4096; l += 256) {
    int o = l >> 6, nn = l & 63;
    size_t a = ((size_t)b * 64 + o) * NPIX + n0 + nn;
    float v = fmaf(vn[a], stats[128 + o], stats[192 + o]);
    vn[a] = v;
    lds[o * 65 + nn] = v;
  }
  __syncthreads();
  for (int l = threadIdx.x; l < 4096; l += 256) {
    int nn = l >> 6, o = l & 63;
    vnT[((size_t)b * NPIX + n0 + nn) * 64 + o] = lds[o * 65 + nn];
  }
}

// ---------------- K3: softmax over N per (b,k) ----------------
__global__ __launch_bounds__(256) void k_softmax(const float* __restrict__ k_pre,
    float* __restrict__ p) {
  int b = blockIdx.y, k = blockIdx.x, t = threadIdx.x;
  const float* src = k_pre + ((size_t)b * 16 + k) * NPIX;
  float v[4];
  float mx = -1e30f;
#pragma unroll
  for (int i = 0; i < 4; ++i) { v[i] = src[t + 256 * i]; mx = fmaxf(mx, v[i]); }
#pragma unroll
  for (int off = 32; off > 0; off >>= 1) mx = fmaxf(mx, __shfl_down(mx, off));
  __shared__ float shm[4], shs[4];
  if ((t & 63) == 0) shm[t >> 6] = mx;
  __syncthreads();
  mx = fmaxf(fmaxf(shm[0], shm[1]), fmaxf(shm[2], shm[3]));
  float s = 0.f;
#pragma unroll
  for (int i = 0; i < 4; ++i) { v[i] = __expf(v[i] - mx); s += v[i]; }
#pragma unroll
  for (int off = 32; off > 0; off >>= 1) s += __shfl_down(s, off);
  if ((t & 63) == 0) shs[t >> 6] = s;
  __syncthreads();
  float r = 1.0f / (shs[0] + shs[1] + shs[2] + shs[3]);
  float* dst = p + ((size_t)b * 16 + k) * NPIX;
#pragma unroll
  for (int i = 0; i < 4; ++i) dst[t + 256 * i] = v[i] * r;
}

// ---------------- K4: lambda_c[b][k][v] ----------------
__global__ __launch_bounds__(256) void k_lambda_c(const float* __restrict__ p,
    const float* __restrict__ vnT, float* __restrict__ lc) {
  __shared__ float pl[1024];
  __shared__ float red[256];
  int b = blockIdx.y, k = blockIdx.x, t = threadIdx.x;
  const float* ps = p + ((size_t)b * 16 + k) * NPIX;
  for (int l = t; l < 1024; l += 256) pl[l] = ps[l];
  __syncthreads();
  int v = t & 63, nq = t >> 6;
  const float* vt = vnT + (size_t)b * NPIX * 64;
  float acc = 0.f;
  for (int n = nq * 256; n < nq * 256 + 256; ++n)
    acc = fmaf(pl[n], vt[(size_t)n * 64 + v], acc);
  red[t] = acc;
  __syncthreads();
  if (t < 64)
    lc[((size_t)b * 16 + k) * 64 + t] = red[t] + red[64 + t] + red[128 + t] + red[192 + t];
}

// ---------------- K5: MFMA implicit-GEMM conv + k-contract + lambda_c + gamma ----
// One block per (b,v). Padded image (54 rows x 64 cols, bf16) stored 4x at
// element shifts 0..3 so every sliding 8-elem window is two aligned ds_read_b64.
// Kernel rows padded 23->32 taps (zeros) so one dr == one MFMA K-step (K=32).
// mfma_f32_16x16x32_bf16 layouts (measured m89/m120):
//   A[m=lane&15][k=quad*8+j], B[k=quad*8+j][n=lane&15], C: col=lane&15 row=quad*4+reg
#define IMG_RS 68            // shorts per padded row (63 used + shift margin)
#define IMG_CS (54 * IMG_RS) // shorts per copy = 3672
__global__ __launch_bounds__(256) void k_main(const float* __restrict__ vn,
    const float* __restrict__ qT, const float* __restrict__ lc,
    const float* __restrict__ emb, const float* __restrict__ gamma,
    float* __restrict__ out) {
  __shared__ __align__(16) short imgc[4 * IMG_CS];   // 29376 B
  __shared__ __align__(16) short embA[23 * 16 * 32]; // 23552 B
  __shared__ float lcv[16];
  int b = blockIdx.y, v = blockIdx.x, t = threadIdx.x;

  // zero image copies (dword writes)
  int* iz = (int*)imgc;
  for (int l = t; l < 2 * IMG_CS; l += 256) iz[l] = 0;
  // emb -> A-operand layout: embA[(dr*16+m)*32 + kd], taps kd>=23 zero
  for (int l = t; l < 23 * 16 * 32; l += 256) {
    int dr = l >> 9, rem = l & 511;
    int m = rem >> 5, kd = rem & 31;
    unsigned short val = 0;
    if (kd < 23) val = f2bf(emb[(size_t)m * 529 + dr * 23 + kd]);
    embA[l] = (short)val;
  }
  if (t < 16) lcv[t] = lc[((size_t)b * 16 + t) * 64 + v];
  __syncthreads();
  // interior fill: copy s stores element e of padded row r at s*IMG_CS + r*68 + e + s
  const float* vsrc = vn + ((size_t)b * 64 + v) * NPIX;
  for (int l = t; l < 4096; l += 256) {
    int s = l >> 10, pix = l & 1023;
    int y = pix >> 5, xx = pix & 31;
    short hv = (short)f2bf(vsrc[pix]);
    imgc[s * IMG_CS + (y + PADR) * IMG_RS + (xx + PADR + s)] = hv;
  }
  __syncthreads();

  int lane = t & 63, wv = t >> 6;
  int nl = lane & 15, quad = lane >> 4;
  int y0 = wv * 8;                          // wave covers image rows y0..y0+7
  int scopy = (4 - (nl & 3)) & 3;           // copy making this lane's windows 8B-aligned
  int colbase = scopy * IMG_CS + nl + quad * 8 + scopy;

  floatx4 acc[16];
#pragma unroll
  for (int i = 0; i < 16; ++i) acc[i] = (floatx4){0.f, 0.f, 0.f, 0.f};

  for (int dr = 0; dr < RR; ++dr) {
    short8v afrag = *(const short8v*)&embA[(dr * 16 + nl) * 32 + quad * 8];
    int rowoff = (y0 + dr) * IMG_RS + colbase;
#pragma unroll
    for (int tt = 0; tt < 16; ++tt) {
      int addr = rowoff + (tt >> 1) * IMG_RS + ((tt & 1) << 4);
      union { short8v s8; short4v s4[2]; } bu;
      bu.s4[0] = *(const short4v*)&imgc[addr];
      bu.s4[1] = *(const short4v*)&imgc[addr + 4];
      acc[tt] = __builtin_amdgcn_mfma_f32_16x16x32_bf16(afrag, bu.s8, acc[tt], 0, 0, 0);
    }
  }

  float g1 = 1.0f + gamma[0];
  float lk0 = lcv[quad * 4 + 0], lk1 = lcv[quad * 4 + 1];
  float lk2 = lcv[quad * 4 + 2], lk3 = lcv[quad * 4 + 3];
#pragma unroll
  for (int tt = 0; tt < 16; ++tt) {
    int y = y0 + (tt >> 1), c0 = (tt & 1) << 4;
    int pix = y * 32 + c0 + nl;
    float lam0 = acc[tt].x + lk0, lam1 = acc[tt].y + lk1;
    float lam2 = acc[tt].z + lk2, lam3 = acc[tt].w + lk3;
    const float* qp = qT + ((size_t)b * NPIX + pix) * 64 + quad * 4;
    float p[4];
#pragma unroll
    for (int h = 0; h < 4; ++h) {
      float4 qv = *(const float4*)(qp + h * 16);
      p[h] = qv.x * lam0 + qv.y * lam1 + qv.z * lam2 + qv.w * lam3;
    }
#pragma unroll
    for (int h = 0; h < 4; ++h) {
      p[h] += __shfl_xor(p[h], 16);
      p[h] += __shfl_xor(p[h], 32);
    }
    float pw = (quad == 0) ? p[0] : (quad == 1) ? p[1] : (quad == 2) ? p[2] : p[3];
    out[((size_t)b * 256 + quad * 64 + v) * NPIX + pix] = g1 * pw;
  }
}

extern "C" void kernel_launch(void* const* d_in, const int* in_sizes, int n_in,
                              void* d_out, int out_size, void* d_ws, size_t ws_size,
                              hipStream_t stream) {
  const float* x      = (const float*)d_in[0];
  const float* Wq     = (const float*)d_in[1];
  const float* bn_q_w = (const float*)d_in[2];
  const float* bn_q_b = (const float*)d_in[3];
  const float* Wk     = (const float*)d_in[4];
  const float* Wv     = (const float*)d_in[5];
  const float* bn_v_w = (const float*)d_in[6];
  const float* bn_v_b = (const float*)d_in[7];
  const float* emb    = (const float*)d_in[8];
  const float* gamma  = (const float*)d_in[9];
  float* out = (float*)d_out;

  float* ws    = (float*)d_ws;
  float* q_pre = ws;                                     // B*64*N
  float* k_pre = q_pre + (size_t)BB * 64 * NPIX;         // B*16*N
  float* vn    = k_pre + (size_t)BB * 16 * NPIX;         // B*64*N
  float* qT    = vn    + (size_t)BB * 64 * NPIX;         // B*N*64
  float* vnT   = qT    + (size_t)BB * NPIX * 64;         // B*N*64
  float* p     = vnT   + (size_t)BB * NPIX * 64;         // B*16*N
  float* lc    = p     + (size_t)BB * 16 * NPIX;         // B*16*64
  float* stats = lc    + (size_t)BB * 16 * 64;           // 256

  k_proj    <<<dim3(32, BB), 256, 0, stream>>>(x, Wq, Wk, Wv, q_pre, k_pre, vn);
  k_bnstats <<<dim3(128),    256, 0, stream>>>(q_pre, vn, bn_q_w, bn_q_b, bn_v_w, bn_v_b, stats);
  k_norm_q  <<<dim3(16, BB), 256, 0, stream>>>(q_pre, stats, qT);
  k_norm_v  <<<dim3(16, BB), 256, 0, stream>>>(vn, stats, vnT);
  k_softmax <<<dim3(16, BB), 256, 0, stream>>>(k_pre, p);
  k_lambda_c<<<dim3(16, BB), 256, 0, stream>>>(p, vnT, lc);
  k_main    <<<dim3(64, BB), 256, 0, stream>>>(vn, qT, lc, emb, gamma, out);
}